// Round 1
// baseline (249.938 us; speedup 1.0000x reference)
//
#include <hip/hip_runtime.h>

#define BB 32
#define KK 1024
#define DD 256

// Kernel 1: per-batch hilbert index + stable counting-sort argsort.
// One block per batch, 256 threads. Keys are in [0,255] (16x16 hilbert grid),
// so a 256-bin stable counting sort exactly reproduces jnp.argsort (stable).
__global__ __launch_bounds__(256) void hilbert_order_kernel(
    const float* __restrict__ centroids,   // [B,K,2]
    float* __restrict__ order_out,         // [B,K] as float
    float* __restrict__ rev_out,           // [B,K] as float
    int* __restrict__ ws_order)            // [B,K] int scratch for gather
{
    __shared__ int key[KK];
    __shared__ int hist[256];
    __shared__ int scanbuf[256];
    __shared__ int ord[KK];

    const int b = blockIdx.x;
    const int t = threadIdx.x;

    hist[t] = 0;
    __syncthreads();

    // Compute hilbert key for elements t, t+256, t+512, t+768.
    // Replicates the reference arithmetic EXACTLY (including s-1-y reflection
    // that can produce negative intermediates; int32 & semantics identical).
    for (int k = t; k < KK; k += 256) {
        const float cxf = centroids[((size_t)b * KK + k) * 2 + 0];
        const float cyf = centroids[((size_t)b * KK + k) * 2 + 1];
        int x = (int)fminf(fmaxf(cxf * 15.0f, 0.0f), 15.0f);
        int y = (int)fminf(fmaxf(cyf * 15.0f, 0.0f), 15.0f);
        int d = 0;
        #pragma unroll
        for (int s = 8; s > 0; s >>= 1) {
            const int rx = ((x & s) != 0) ? 1 : 0;
            const int ry = ((y & s) != 0) ? 1 : 0;
            d += s * s * ((3 * rx) ^ ry);
            if (ry == 0) {                 // swap (rotate quadrant)
                if (rx == 1) {             // and reflect
                    const int nx = s - 1 - y;
                    const int ny = s - 1 - x;
                    x = nx; y = ny;
                } else {
                    const int tmp = x; x = y; y = tmp;
                }
            }
        }
        key[k] = d;
        atomicAdd(&hist[d], 1);
    }
    __syncthreads();

    // Hillis-Steele inclusive scan over the 256 bins, then make exclusive.
    scanbuf[t] = hist[t];
    __syncthreads();
    #pragma unroll
    for (int off = 1; off < 256; off <<= 1) {
        const int v = (t >= off) ? scanbuf[t - off] : 0;
        __syncthreads();
        scanbuf[t] += v;
        __syncthreads();
    }
    int base = scanbuf[t] - hist[t];   // exclusive prefix for bin t

    // Stable scatter: thread t owns bin t; scan keys in original index order.
    // key[j] read is wave-uniform (LDS broadcast); write is predicated.
    for (int j = 0; j < KK; ++j) {
        if (key[j] == t) { ord[base] = j; ++base; }
    }
    __syncthreads();

    // Emit order (float), reverse_order (float), and int order for gather.
    for (int r = t; r < KK; r += 256) {
        const int o = ord[r];
        order_out[b * KK + r] = (float)o;
        rev_out[b * KK + o]   = (float)r;   // exact permutation inverse
        ws_order[b * KK + r]  = o;
    }
}

// Kernel 2: ordered_slots[b, r, :] = slots[b, order[b][r], :]
// 64 lanes per row (256 floats = 64 float4), 4 rows per 256-thread block.
__global__ __launch_bounds__(256) void gather_rows_kernel(
    const float4* __restrict__ slots,     // [B*K, 64] float4
    const int* __restrict__ ws_order,     // [B*K]
    float4* __restrict__ out)             // [B*K, 64] float4
{
    const int row  = blockIdx.x * 4 + (threadIdx.x >> 6);   // [0, B*K)
    const int lane = threadIdx.x & 63;
    const int b    = row >> 10;
    const int src  = ws_order[row];                          // wave-uniform
    const float4* sp = slots + ((size_t)(b * KK + src)) * (DD / 4);
    float4*       dp = out   + ((size_t)row) * (DD / 4);
    dp[lane] = sp[lane];
}

extern "C" void kernel_launch(void* const* d_in, const int* in_sizes, int n_in,
                              void* d_out, int out_size, void* d_ws, size_t ws_size,
                              hipStream_t stream) {
    const float* slots     = (const float*)d_in[0];   // [32,1024,256]
    // d_in[1] = adj  — unused by the reference; never read (128 MB saved)
    const float* centroids = (const float*)d_in[2];   // [32,1024,2]

    float* out          = (float*)d_out;
    float* ordered      = out;                               // 8388608 floats
    float* order_out    = out + (size_t)BB * KK * DD;        // 32768 floats
    float* rev_out      = order_out + (size_t)BB * KK;       // 32768 floats
    int*   ws_order     = (int*)d_ws;                        // 128 KB scratch

    hilbert_order_kernel<<<BB, 256, 0, stream>>>(centroids, order_out, rev_out, ws_order);

    const int rows = BB * KK;                 // 32768 rows
    gather_rows_kernel<<<rows / 4, 256, 0, stream>>>(
        (const float4*)slots, ws_order, (float4*)ordered);
}